// Round 1
// baseline (1724.855 us; speedup 1.0000x reference)
//
#include <hip/hip_runtime.h>

// ---------------------------------------------------------------------------
// PoseProjection: T = inv(current) @ historical; trilinear grid_sample of
// features[8,32,48,96,96], sdf[8,1,...], occ[8,1,...] at the transformed
// voxel grid; also outputs the normalized grid [8,48,96,96,3].
// Outputs concatenated: feat(113246208) | sdf(3538944) | occ(3538944) | grid(10616832)
// ---------------------------------------------------------------------------

#define XD 96
#define YD 96
#define ZD 48
#define BD 8
#define CD 32

constexpr float VOX = 0.0625f;
constexpr int   HW   = YD * XD;          // 9216
constexpr int   DHW  = ZD * HW;          // 442368
constexpr long long FEAT_N = (long long)BD * CD * DHW;  // 113246208
constexpr long long SDF_N  = (long long)BD * DHW;       // 3538944
constexpr int BLOCKS_PER_B = DHW / 256;  // 1728 (exact)

// --- Kernel 1: per-batch transform via double-precision adjugate inverse ---
__global__ void make_transform_kernel(const float* __restrict__ hist,
                                      const float* __restrict__ cur,
                                      float* __restrict__ T12) {
    int b = threadIdx.x;
    if (b >= BD) return;
    double m[16], inv[16];
    #pragma unroll
    for (int i = 0; i < 16; ++i) m[i] = (double)cur[b * 16 + i];

    inv[0]  =  m[5]*m[10]*m[15] - m[5]*m[11]*m[14] - m[9]*m[6]*m[15] + m[9]*m[7]*m[14] + m[13]*m[6]*m[11] - m[13]*m[7]*m[10];
    inv[4]  = -m[4]*m[10]*m[15] + m[4]*m[11]*m[14] + m[8]*m[6]*m[15] - m[8]*m[7]*m[14] - m[12]*m[6]*m[11] + m[12]*m[7]*m[10];
    inv[8]  =  m[4]*m[9]*m[15]  - m[4]*m[11]*m[13] - m[8]*m[5]*m[15] + m[8]*m[7]*m[13] + m[12]*m[5]*m[11] - m[12]*m[7]*m[9];
    inv[12] = -m[4]*m[9]*m[14]  + m[4]*m[10]*m[13] + m[8]*m[5]*m[14] - m[8]*m[6]*m[13] - m[12]*m[5]*m[10] + m[12]*m[6]*m[9];
    inv[1]  = -m[1]*m[10]*m[15] + m[1]*m[11]*m[14] + m[9]*m[2]*m[15] - m[9]*m[3]*m[14] - m[13]*m[2]*m[11] + m[13]*m[3]*m[10];
    inv[5]  =  m[0]*m[10]*m[15] - m[0]*m[11]*m[14] - m[8]*m[2]*m[15] + m[8]*m[3]*m[14] + m[12]*m[2]*m[11] - m[12]*m[3]*m[10];
    inv[9]  = -m[0]*m[9]*m[15]  + m[0]*m[11]*m[13] + m[8]*m[1]*m[15] - m[8]*m[3]*m[13] - m[12]*m[1]*m[11] + m[12]*m[3]*m[9];
    inv[13] =  m[0]*m[9]*m[14]  - m[0]*m[10]*m[13] - m[8]*m[1]*m[14] + m[8]*m[2]*m[13] + m[12]*m[1]*m[10] - m[12]*m[2]*m[9];
    inv[2]  =  m[1]*m[6]*m[15]  - m[1]*m[7]*m[14]  - m[5]*m[2]*m[15] + m[5]*m[3]*m[14] + m[13]*m[2]*m[7]  - m[13]*m[3]*m[6];
    inv[6]  = -m[0]*m[6]*m[15]  + m[0]*m[7]*m[14]  + m[4]*m[2]*m[15] - m[4]*m[3]*m[14] - m[12]*m[2]*m[7]  + m[12]*m[3]*m[6];
    inv[10] =  m[0]*m[5]*m[15]  - m[0]*m[7]*m[13]  - m[4]*m[1]*m[15] + m[4]*m[3]*m[13] + m[12]*m[1]*m[7]  - m[12]*m[3]*m[5];
    inv[14] = -m[0]*m[5]*m[14]  + m[0]*m[6]*m[13]  + m[4]*m[1]*m[14] - m[4]*m[2]*m[13] - m[12]*m[1]*m[6]  + m[12]*m[2]*m[5];
    inv[3]  = -m[1]*m[6]*m[11]  + m[1]*m[7]*m[10]  + m[5]*m[2]*m[11] - m[5]*m[3]*m[10] - m[9]*m[2]*m[7]   + m[9]*m[3]*m[6];
    inv[7]  =  m[0]*m[6]*m[11]  - m[0]*m[7]*m[10]  - m[4]*m[2]*m[11] + m[4]*m[3]*m[10] + m[8]*m[2]*m[7]   - m[8]*m[3]*m[6];
    inv[11] = -m[0]*m[5]*m[11]  + m[0]*m[7]*m[9]   + m[4]*m[1]*m[11] - m[4]*m[3]*m[9]  - m[8]*m[1]*m[7]   + m[8]*m[3]*m[5];
    inv[15] =  m[0]*m[5]*m[10]  - m[0]*m[6]*m[9]   - m[4]*m[1]*m[10] + m[4]*m[2]*m[9]  + m[8]*m[1]*m[6]   - m[8]*m[2]*m[5];

    double det = m[0]*inv[0] + m[1]*inv[4] + m[2]*inv[8] + m[3]*inv[12];
    double rdet = 1.0 / det;
    #pragma unroll
    for (int i = 0; i < 16; ++i) inv[i] *= rdet;

    // T = inv(cur) @ hist ; store rows 0..2 (row 3 is 0,0,0,1)
    #pragma unroll
    for (int i = 0; i < 3; ++i) {
        #pragma unroll
        for (int j = 0; j < 4; ++j) {
            double s = 0.0;
            #pragma unroll
            for (int k = 0; k < 4; ++k)
                s += inv[i * 4 + k] * (double)hist[b * 16 + k * 4 + j];
            T12[b * 12 + i * 4 + j] = (float)s;
        }
    }
}

// --- Kernel 2: fused grid computation + trilinear sampling of 34 channels ---
__global__ __launch_bounds__(256) void proj_kernel(
    const float* __restrict__ feat,
    const float* __restrict__ sdf,
    const float* __restrict__ occ,
    const float* __restrict__ T12,
    float* __restrict__ out) {

    // b, z are block-uniform (1728 blocks per batch, 36 blocks per z-slice)
    const int b   = blockIdx.x / BLOCKS_PER_B;          // SGPR
    const int rem = blockIdx.x % BLOCKS_PER_B;
    const int zyx = rem * 256 + threadIdx.x;            // in-batch flat [0, DHW)
    const int x   = zyx % XD;
    const int t1  = zyx / XD;
    const int y   = t1 % YD;
    const int z   = t1 / YD;

    // transform rows (scalar loads — b uniform per block)
    const float* Tb = T12 + b * 12;
    const float px = x * VOX, py = y * VOX, pz = z * VOX;
    const float hx = Tb[0] * px + Tb[1] * py + Tb[2]  * pz + Tb[3];
    const float hy = Tb[4] * px + Tb[5] * py + Tb[6]  * pz + Tb[7];
    const float hz = Tb[8] * px + Tb[9] * py + Tb[10] * pz + Tb[11];

    // normalized coords, reference op order: 2*((h/VOX)/norm) - 1
    const float nx = 2.0f * ((hx / VOX) / 95.0f) - 1.0f;
    const float ny = 2.0f * ((hy / VOX) / 95.0f) - 1.0f;
    const float nz = 2.0f * ((hz / VOX) / 47.0f) - 1.0f;

    // grid output: [B,D,H,W,3] at (b,z,y,x)
    {
        const long long gbase = FEAT_N + 2 * SDF_N + ((long long)b * DHW + zyx) * 3;
        out[gbase + 0] = nx;
        out[gbase + 1] = ny;
        out[gbase + 2] = nz;
    }

    // sample coords (align_corners=True)
    const float ix = (nx + 1.0f) * 0.5f * 95.0f;
    const float iy = (ny + 1.0f) * 0.5f * 95.0f;
    const float iz = (nz + 1.0f) * 0.5f * 47.0f;

    const float x0f = floorf(ix), y0f = floorf(iy), z0f = floorf(iz);
    const float fx = ix - x0f, fy = iy - y0f, fz = iz - z0f;

    const float wXa[2] = {1.0f - fx, fx};
    const float wYa[2] = {1.0f - fy, fy};
    const float wZa[2] = {1.0f - fz, fz};

    int   cX[2], cY[2], cZ[2];
    bool  vX[2], vY[2], vZ[2];
    #pragma unroll
    for (int d = 0; d < 2; ++d) {
        const float xi = x0f + (float)d;
        const float yi = y0f + (float)d;
        const float zi = z0f + (float)d;
        vX[d] = (xi >= 0.0f) && (xi <= 95.0f);
        vY[d] = (yi >= 0.0f) && (yi <= 95.0f);
        vZ[d] = (zi >= 0.0f) && (zi <= 47.0f);
        cX[d] = (int)fminf(fmaxf(xi, 0.0f), 95.0f);
        cY[d] = (int)fminf(fmaxf(yi, 0.0f), 95.0f);
        cZ[d] = (int)fminf(fmaxf(zi, 0.0f), 47.0f);
    }

    // 8 taps, reference loop order: dx outer, dy, dz inner
    int   offs[8];
    float wts[8];
    #pragma unroll
    for (int j = 0; j < 8; ++j) {
        const int dx = (j >> 2) & 1, dy = (j >> 1) & 1, dz = j & 1;
        offs[j] = cZ[dz] * HW + cY[dy] * XD + cX[dx];
        float w = (wXa[dx] * wYa[dy]) * wZa[dz];
        wts[j] = (vX[dx] && vY[dy] && vZ[dz]) ? w : 0.0f;
    }

    // features: 32 channels
    const float* fb = feat + (long long)b * CD * DHW;
    float* ob = out + (long long)b * CD * DHW + zyx;
    #pragma unroll 4
    for (int c = 0; c < CD; ++c) {
        const float* p = fb + (long long)c * DHW;
        float acc = 0.0f;
        #pragma unroll
        for (int j = 0; j < 8; ++j) acc += p[offs[j]] * wts[j];
        ob[(long long)c * DHW] = acc;
    }

    // sdf (1 channel)
    {
        const float* p = sdf + (long long)b * DHW;
        float acc = 0.0f;
        #pragma unroll
        for (int j = 0; j < 8; ++j) acc += p[offs[j]] * wts[j];
        out[FEAT_N + (long long)b * DHW + zyx] = acc;
    }
    // occupancy (1 channel)
    {
        const float* p = occ + (long long)b * DHW;
        float acc = 0.0f;
        #pragma unroll
        for (int j = 0; j < 8; ++j) acc += p[offs[j]] * wts[j];
        out[FEAT_N + SDF_N + (long long)b * DHW + zyx] = acc;
    }
}

extern "C" void kernel_launch(void* const* d_in, const int* in_sizes, int n_in,
                              void* d_out, int out_size, void* d_ws, size_t ws_size,
                              hipStream_t stream) {
    const float* feat = (const float*)d_in[0];
    const float* sdf  = (const float*)d_in[1];
    const float* occ  = (const float*)d_in[2];
    const float* hist = (const float*)d_in[3];
    const float* cur  = (const float*)d_in[4];
    float* out = (float*)d_out;
    float* T12 = (float*)d_ws;   // 8 * 12 floats

    make_transform_kernel<<<1, BD, 0, stream>>>(hist, cur, T12);
    proj_kernel<<<BD * BLOCKS_PER_B, 256, 0, stream>>>(feat, sdf, occ, T12, out);
}

// Round 2
// 1466.026 us; speedup vs baseline: 1.1766x; 1.1766x over previous
//
#include <hip/hip_runtime.h>

// ---------------------------------------------------------------------------
// PoseProjection: T = inv(current) @ historical; trilinear grid_sample of
// features[8,32,48,96,96], sdf[8,1,...], occ[8,1,...] at the transformed
// voxel grid; also outputs the normalized grid [8,48,96,96,3].
// Outputs concatenated: feat(113246208) | sdf(3538944) | occ(3538944) | grid(10616832)
//
// R2 strategy: the R1 kernel was vector-memory TRANSACTION bound (VALUBusy 5%,
// HBM 7.5%, occupancy 90%): 8 taps x 34 channels of scattered scalar gathers.
// Fix: transpose features to channels-last (feat_t[B,DHW,32], sdf+occ ->
// so_t[B,DHW,2]) in workspace, then gather with wave = 2 voxels x 32
// channel-lanes so each tap is a 128B contiguous read (4 transactions/wave-load
// instead of ~64). Coalesced output via LDS transpose.
// ---------------------------------------------------------------------------

#define XD 96
#define YD 96
#define ZD 48
#define BD 8
#define CD 32

constexpr float VOX = 0.0625f;
constexpr int   HW   = YD * XD;          // 9216
constexpr int   DHW  = ZD * HW;          // 442368
constexpr long long FEAT_N = (long long)BD * CD * DHW;  // 113246208
constexpr long long SDF_N  = (long long)BD * DHW;       // 3538944
constexpr long long GRID_OFF = FEAT_N + 2 * SDF_N;

// --- Kernel 1: per-batch transform via double-precision adjugate inverse ---
__global__ void make_transform_kernel(const float* __restrict__ hist,
                                      const float* __restrict__ cur,
                                      float* __restrict__ T12) {
    int b = threadIdx.x;
    if (b >= BD) return;
    double m[16], inv[16];
    #pragma unroll
    for (int i = 0; i < 16; ++i) m[i] = (double)cur[b * 16 + i];

    inv[0]  =  m[5]*m[10]*m[15] - m[5]*m[11]*m[14] - m[9]*m[6]*m[15] + m[9]*m[7]*m[14] + m[13]*m[6]*m[11] - m[13]*m[7]*m[10];
    inv[4]  = -m[4]*m[10]*m[15] + m[4]*m[11]*m[14] + m[8]*m[6]*m[15] - m[8]*m[7]*m[14] - m[12]*m[6]*m[11] + m[12]*m[7]*m[10];
    inv[8]  =  m[4]*m[9]*m[15]  - m[4]*m[11]*m[13] - m[8]*m[5]*m[15] + m[8]*m[7]*m[13] + m[12]*m[5]*m[11] - m[12]*m[7]*m[9];
    inv[12] = -m[4]*m[9]*m[14]  + m[4]*m[10]*m[13] + m[8]*m[5]*m[14] - m[8]*m[6]*m[13] - m[12]*m[5]*m[10] + m[12]*m[6]*m[9];
    inv[1]  = -m[1]*m[10]*m[15] + m[1]*m[11]*m[14] + m[9]*m[2]*m[15] - m[9]*m[3]*m[14] - m[13]*m[2]*m[11] + m[13]*m[3]*m[10];
    inv[5]  =  m[0]*m[10]*m[15] - m[0]*m[11]*m[14] - m[8]*m[2]*m[15] + m[8]*m[3]*m[14] + m[12]*m[2]*m[11] - m[12]*m[3]*m[10];
    inv[9]  = -m[0]*m[9]*m[15]  + m[0]*m[11]*m[13] + m[8]*m[1]*m[15] - m[8]*m[3]*m[13] - m[12]*m[1]*m[11] + m[12]*m[3]*m[9];
    inv[13] =  m[0]*m[9]*m[14]  - m[0]*m[10]*m[13] - m[8]*m[1]*m[14] + m[8]*m[2]*m[13] + m[12]*m[1]*m[10] - m[12]*m[2]*m[9];
    inv[2]  =  m[1]*m[6]*m[15]  - m[1]*m[7]*m[14]  - m[5]*m[2]*m[15] + m[5]*m[3]*m[14] + m[13]*m[2]*m[7]  - m[13]*m[3]*m[6];
    inv[6]  = -m[0]*m[6]*m[15]  + m[0]*m[7]*m[14]  + m[4]*m[2]*m[15] - m[4]*m[3]*m[14] - m[12]*m[2]*m[7]  + m[12]*m[3]*m[6];
    inv[10] =  m[0]*m[5]*m[15]  - m[0]*m[7]*m[13]  - m[4]*m[1]*m[15] + m[4]*m[3]*m[13] + m[12]*m[1]*m[7]  - m[12]*m[3]*m[5];
    inv[14] = -m[0]*m[5]*m[14]  + m[0]*m[6]*m[13]  + m[4]*m[1]*m[14] - m[4]*m[2]*m[13] - m[12]*m[1]*m[6]  + m[12]*m[2]*m[5];
    inv[3]  = -m[1]*m[6]*m[11]  + m[1]*m[7]*m[10]  + m[5]*m[2]*m[11] - m[5]*m[3]*m[10] - m[9]*m[2]*m[7]   + m[9]*m[3]*m[6];
    inv[7]  =  m[0]*m[6]*m[11]  - m[0]*m[7]*m[10]  - m[4]*m[2]*m[11] + m[4]*m[3]*m[10] + m[8]*m[2]*m[7]   - m[8]*m[3]*m[6];
    inv[11] = -m[0]*m[5]*m[11]  + m[0]*m[7]*m[9]   + m[4]*m[1]*m[11] - m[4]*m[3]*m[9]  - m[8]*m[1]*m[7]   + m[8]*m[3]*m[5];
    inv[15] =  m[0]*m[5]*m[10]  - m[0]*m[6]*m[9]   - m[4]*m[1]*m[10] + m[4]*m[2]*m[9]  + m[8]*m[1]*m[6]   - m[8]*m[2]*m[5];

    double det = m[0]*inv[0] + m[1]*inv[4] + m[2]*inv[8] + m[3]*inv[12];
    double rdet = 1.0 / det;
    #pragma unroll
    for (int i = 0; i < 16; ++i) inv[i] *= rdet;

    // T = inv(cur) @ hist ; store rows 0..2 (row 3 is 0,0,0,1)
    #pragma unroll
    for (int i = 0; i < 3; ++i) {
        #pragma unroll
        for (int j = 0; j < 4; ++j) {
            double s = 0.0;
            #pragma unroll
            for (int k = 0; k < 4; ++k)
                s += inv[i * 4 + k] * (double)hist[b * 16 + k * 4 + j];
            T12[b * 12 + i * 4 + j] = (float)s;
        }
    }
}

// --- Pass A: transpose features to channels-last + pack sdf/occ as float2 ---
__global__ __launch_bounds__(256) void transpose_kernel(
    const float* __restrict__ feat,
    const float* __restrict__ sdf,
    const float* __restrict__ occ,
    float* __restrict__ feat_t,
    float2* __restrict__ so_t) {

    __shared__ float tile[64][33];
    const int b     = blockIdx.x / (DHW / 64);
    const int vbase = (blockIdx.x % (DHW / 64)) * 64;
    const int tid   = threadIdx.x;

    // read: coalesced along v, 4 channel-groups x 8
    const int vv = tid & 63, cc = tid >> 6;
    const size_t inb = (size_t)b * CD * DHW;
    #pragma unroll
    for (int it = 0; it < 8; ++it) {
        const int c = cc * 8 + it;
        tile[vv][c] = feat[inb + (size_t)c * DHW + vbase + vv];
    }
    // sdf/occ packing (wave 0 only), dense float2 stores
    if (tid < 64) {
        const size_t v = (size_t)b * DHW + vbase + tid;
        so_t[v] = make_float2(sdf[v], occ[v]);
    }
    __syncthreads();

    // write: channels-last, 32 consecutive lanes = 128B contiguous
    const int c  = tid & 31, vg = tid >> 5;
    const size_t ob = (size_t)b * DHW + vbase;
    #pragma unroll
    for (int k = 0; k < 8; ++k) {
        const int vl = vg * 8 + k;
        feat_t[(ob + vl) * 32 + c] = tile[vl][c];
    }
}

// --- Pass B: cooperative gather, wave = 2 voxels x 32 channel-lanes ---
__global__ __launch_bounds__(256) void proj2_kernel(
    const float* __restrict__ feat_t,
    const float2* __restrict__ so_t,
    const float* __restrict__ T12,
    float* __restrict__ out) {

    __shared__ float2 ow[128][9];     // (off32 bit-cast, weight) per voxel/tap; pad 9 vs write conflicts
    __shared__ float  tile[128][33];  // feature results, pad 33 for transpose write
    __shared__ float  soL[128][2];

    const int b     = blockIdx.x / (DHW / 128);
    const int vbase = (blockIdx.x % (DHW / 128)) * 128;
    const int tid   = threadIdx.x;
    const int bDHW  = b * DHW;

    // ---- Phase 1: one thread per voxel computes grid coords, taps, weights ----
    if (tid < 128) {
        const int v  = vbase + tid;
        const int x  = v % XD;
        const int t1 = v / XD;
        const int y  = t1 % YD;
        const int z  = t1 / YD;

        const float* Tb = T12 + b * 12;
        const float px = x * VOX, py = y * VOX, pz = z * VOX;
        const float hx = Tb[0] * px + Tb[1] * py + Tb[2]  * pz + Tb[3];
        const float hy = Tb[4] * px + Tb[5] * py + Tb[6]  * pz + Tb[7];
        const float hz = Tb[8] * px + Tb[9] * py + Tb[10] * pz + Tb[11];

        // normalized coords, reference op order: 2*((h/VOX)/norm) - 1
        const float nx = 2.0f * ((hx / VOX) / 95.0f) - 1.0f;
        const float ny = 2.0f * ((hy / VOX) / 95.0f) - 1.0f;
        const float nz = 2.0f * ((hz / VOX) / 47.0f) - 1.0f;

        // grid output [B,D,H,W,3]
        float* g = out + GRID_OFF + ((size_t)bDHW + v) * 3;
        g[0] = nx; g[1] = ny; g[2] = nz;

        // sample coords (align_corners=True)
        const float ix = (nx + 1.0f) * 0.5f * 95.0f;
        const float iy = (ny + 1.0f) * 0.5f * 95.0f;
        const float iz = (nz + 1.0f) * 0.5f * 47.0f;

        const float x0f = floorf(ix), y0f = floorf(iy), z0f = floorf(iz);
        const float fx = ix - x0f, fy = iy - y0f, fz = iz - z0f;

        const float wXa[2] = {1.0f - fx, fx};
        const float wYa[2] = {1.0f - fy, fy};
        const float wZa[2] = {1.0f - fz, fz};

        int  cX[2], cY[2], cZ[2];
        bool vX[2], vY[2], vZ[2];
        #pragma unroll
        for (int d = 0; d < 2; ++d) {
            const float xi = x0f + (float)d;
            const float yi = y0f + (float)d;
            const float zi = z0f + (float)d;
            vX[d] = (xi >= 0.0f) && (xi <= 95.0f);
            vY[d] = (yi >= 0.0f) && (yi <= 95.0f);
            vZ[d] = (zi >= 0.0f) && (zi <= 47.0f);
            cX[d] = (int)fminf(fmaxf(xi, 0.0f), 95.0f);
            cY[d] = (int)fminf(fmaxf(yi, 0.0f), 95.0f);
            cZ[d] = (int)fminf(fmaxf(zi, 0.0f), 47.0f);
        }

        #pragma unroll
        for (int j = 0; j < 8; ++j) {
            const int dx = (j >> 2) & 1, dy = (j >> 1) & 1, dz = j & 1;
            const int off = cZ[dz] * HW + cY[dy] * XD + cX[dx];
            const int off32 = (bDHW + off) * 32;   // float index into feat_t (fits int32)
            float w = (wXa[dx] * wYa[dy]) * wZa[dz];
            w = (vX[dx] && vY[dy] && vZ[dz]) ? w : 0.0f;
            ow[tid][j] = make_float2(__int_as_float(off32), w);
        }
    }
    __syncthreads();

    // ---- Phase 2: cooperative gather. lane = (voxel-half, channel) ----
    const int w     = tid >> 6;          // wave id 0..3 -> 32-voxel chunk
    const int vhalf = (tid >> 5) & 1;
    const int c     = tid & 31;
    const float* sp = (const float*)so_t;

    #pragma unroll 1
    for (int s = 0; s < 16; ++s) {
        const int vl = w * 32 + s * 2 + vhalf;
        float acc = 0.0f;
        float a2  = 0.0f;
        #pragma unroll
        for (int j = 0; j < 8; ++j) {
            const float2 p = ow[vl][j];            // broadcast read (32 lanes same addr)
            const int off32 = __float_as_int(p.x);
            acc = fmaf(feat_t[(size_t)off32 + c], p.y, acc);
            if (c < 2) {
                const int off2 = off32 >> 4;       // (bDHW+off)*2
                a2 = fmaf(sp[(size_t)off2 + c], p.y, a2);
            }
        }
        tile[vl][c] = acc;
        if (c < 2) soL[vl][c] = a2;
    }
    __syncthreads();

    // ---- coalesced output writes ----
    float* ob = out + (size_t)b * CD * DHW + vbase;
    #pragma unroll
    for (int k = 0; k < 16; ++k) {
        const int cch = (tid >> 6) + 4 * (k & 7);
        const int vl  = (tid & 63) + 64 * (k >> 3);
        ob[(size_t)cch * DHW + vl] = tile[vl][cch];
    }
    {
        const int ch = tid >> 7, vl = tid & 127;
        out[FEAT_N + (size_t)ch * SDF_N + bDHW + vbase + vl] = soL[vl][ch];
    }
}

// --- Fallback (R1 kernel) if workspace is too small for the transpose ---
__global__ __launch_bounds__(256) void proj_kernel(
    const float* __restrict__ feat,
    const float* __restrict__ sdf,
    const float* __restrict__ occ,
    const float* __restrict__ T12,
    float* __restrict__ out) {

    const int b   = blockIdx.x / (DHW / 256);
    const int rem = blockIdx.x % (DHW / 256);
    const int zyx = rem * 256 + threadIdx.x;
    const int x   = zyx % XD;
    const int t1  = zyx / XD;
    const int y   = t1 % YD;
    const int z   = t1 / YD;

    const float* Tb = T12 + b * 12;
    const float px = x * VOX, py = y * VOX, pz = z * VOX;
    const float hx = Tb[0] * px + Tb[1] * py + Tb[2]  * pz + Tb[3];
    const float hy = Tb[4] * px + Tb[5] * py + Tb[6]  * pz + Tb[7];
    const float hz = Tb[8] * px + Tb[9] * py + Tb[10] * pz + Tb[11];

    const float nx = 2.0f * ((hx / VOX) / 95.0f) - 1.0f;
    const float ny = 2.0f * ((hy / VOX) / 95.0f) - 1.0f;
    const float nz = 2.0f * ((hz / VOX) / 47.0f) - 1.0f;

    {
        const long long gbase = GRID_OFF + ((long long)b * DHW + zyx) * 3;
        out[gbase + 0] = nx;
        out[gbase + 1] = ny;
        out[gbase + 2] = nz;
    }

    const float ix = (nx + 1.0f) * 0.5f * 95.0f;
    const float iy = (ny + 1.0f) * 0.5f * 95.0f;
    const float iz = (nz + 1.0f) * 0.5f * 47.0f;

    const float x0f = floorf(ix), y0f = floorf(iy), z0f = floorf(iz);
    const float fx = ix - x0f, fy = iy - y0f, fz = iz - z0f;

    const float wXa[2] = {1.0f - fx, fx};
    const float wYa[2] = {1.0f - fy, fy};
    const float wZa[2] = {1.0f - fz, fz};

    int  cX[2], cY[2], cZ[2];
    bool vX[2], vY[2], vZ[2];
    #pragma unroll
    for (int d = 0; d < 2; ++d) {
        const float xi = x0f + (float)d;
        const float yi = y0f + (float)d;
        const float zi = z0f + (float)d;
        vX[d] = (xi >= 0.0f) && (xi <= 95.0f);
        vY[d] = (yi >= 0.0f) && (yi <= 95.0f);
        vZ[d] = (zi >= 0.0f) && (zi <= 47.0f);
        cX[d] = (int)fminf(fmaxf(xi, 0.0f), 95.0f);
        cY[d] = (int)fminf(fmaxf(yi, 0.0f), 95.0f);
        cZ[d] = (int)fminf(fmaxf(zi, 0.0f), 47.0f);
    }

    int   offs[8];
    float wts[8];
    #pragma unroll
    for (int j = 0; j < 8; ++j) {
        const int dx = (j >> 2) & 1, dy = (j >> 1) & 1, dz = j & 1;
        offs[j] = cZ[dz] * HW + cY[dy] * XD + cX[dx];
        float w = (wXa[dx] * wYa[dy]) * wZa[dz];
        wts[j] = (vX[dx] && vY[dy] && vZ[dz]) ? w : 0.0f;
    }

    const float* fb = feat + (long long)b * CD * DHW;
    float* ob = out + (long long)b * CD * DHW + zyx;
    #pragma unroll 4
    for (int cc = 0; cc < CD; ++cc) {
        const float* p = fb + (long long)cc * DHW;
        float acc = 0.0f;
        #pragma unroll
        for (int j = 0; j < 8; ++j) acc += p[offs[j]] * wts[j];
        ob[(long long)cc * DHW] = acc;
    }
    {
        const float* p = sdf + (long long)b * DHW;
        float acc = 0.0f;
        #pragma unroll
        for (int j = 0; j < 8; ++j) acc += p[offs[j]] * wts[j];
        out[FEAT_N + (long long)b * DHW + zyx] = acc;
    }
    {
        const float* p = occ + (long long)b * DHW;
        float acc = 0.0f;
        #pragma unroll
        for (int j = 0; j < 8; ++j) acc += p[offs[j]] * wts[j];
        out[FEAT_N + SDF_N + (long long)b * DHW + zyx] = acc;
    }
}

extern "C" void kernel_launch(void* const* d_in, const int* in_sizes, int n_in,
                              void* d_out, int out_size, void* d_ws, size_t ws_size,
                              hipStream_t stream) {
    const float* feat = (const float*)d_in[0];
    const float* sdf  = (const float*)d_in[1];
    const float* occ  = (const float*)d_in[2];
    const float* hist = (const float*)d_in[3];
    const float* cur  = (const float*)d_in[4];
    float* out = (float*)d_out;

    const size_t need = (size_t)(FEAT_N + 2 * SDF_N) * sizeof(float) + 512;

    if (ws_size >= need) {
        float*  feat_t = (float*)d_ws;                    // [B,DHW,32]
        float2* so_t   = (float2*)((char*)d_ws + (size_t)FEAT_N * sizeof(float));  // [B,DHW] {sdf,occ}
        float*  T12    = (float*)((char*)d_ws + (size_t)(FEAT_N + 2 * SDF_N) * sizeof(float));

        make_transform_kernel<<<1, BD, 0, stream>>>(hist, cur, T12);
        transpose_kernel<<<BD * (DHW / 64), 256, 0, stream>>>(feat, sdf, occ, feat_t, so_t);
        proj2_kernel<<<BD * (DHW / 128), 256, 0, stream>>>(feat_t, so_t, T12, out);
    } else {
        float* T12 = (float*)d_ws;
        make_transform_kernel<<<1, BD, 0, stream>>>(hist, cur, T12);
        proj_kernel<<<BD * (DHW / 256), 256, 0, stream>>>(feat, sdf, occ, T12, out);
    }
}

// Round 3
// 1107.058 us; speedup vs baseline: 1.5581x; 1.3243x over previous
//
#include <hip/hip_runtime.h>

// ---------------------------------------------------------------------------
// PoseProjection: T = inv(current) @ historical; trilinear grid_sample of
// features[8,32,48,96,96], sdf[8,1,...], occ[8,1,...] at the transformed
// voxel grid; also outputs the normalized grid [8,48,96,96,3].
// Outputs concatenated: feat(113246208) | sdf(3538944) | occ(3538944) | grid(10616832)
//
// R3: R2 showed both passes instruction-bound (proj2: HBM 10%, VALU 34%,
// occ 58%; transpose ~1.2 TB/s) — all global traffic was scalar 4B.
// This round vectorizes both passes to float4 on the global side:
//   - transpose: float4 read along v / float4 write along c via LDS tile
//   - proj2: lane = (voxel, channel-quad); each tap = one float4 load
//     (32 gather instrs/thread instead of 128)
// ---------------------------------------------------------------------------

#define XD 96
#define YD 96
#define ZD 48
#define BD 8
#define CD 32

constexpr float VOX = 0.0625f;
constexpr int   HW   = YD * XD;          // 9216
constexpr int   DHW  = ZD * HW;          // 442368
constexpr long long FEAT_N = (long long)BD * CD * DHW;  // 113246208
constexpr long long SDF_N  = (long long)BD * DHW;       // 3538944
constexpr long long GRID_OFF = FEAT_N + 2 * SDF_N;

// --- Kernel 1: per-batch transform via double-precision adjugate inverse ---
__global__ void make_transform_kernel(const float* __restrict__ hist,
                                      const float* __restrict__ cur,
                                      float* __restrict__ T12) {
    int b = threadIdx.x;
    if (b >= BD) return;
    double m[16], inv[16];
    #pragma unroll
    for (int i = 0; i < 16; ++i) m[i] = (double)cur[b * 16 + i];

    inv[0]  =  m[5]*m[10]*m[15] - m[5]*m[11]*m[14] - m[9]*m[6]*m[15] + m[9]*m[7]*m[14] + m[13]*m[6]*m[11] - m[13]*m[7]*m[10];
    inv[4]  = -m[4]*m[10]*m[15] + m[4]*m[11]*m[14] + m[8]*m[6]*m[15] - m[8]*m[7]*m[14] - m[12]*m[6]*m[11] + m[12]*m[7]*m[10];
    inv[8]  =  m[4]*m[9]*m[15]  - m[4]*m[11]*m[13] - m[8]*m[5]*m[15] + m[8]*m[7]*m[13] + m[12]*m[5]*m[11] - m[12]*m[7]*m[9];
    inv[12] = -m[4]*m[9]*m[14]  + m[4]*m[10]*m[13] + m[8]*m[5]*m[14] - m[8]*m[6]*m[13] - m[12]*m[5]*m[10] + m[12]*m[6]*m[9];
    inv[1]  = -m[1]*m[10]*m[15] + m[1]*m[11]*m[14] + m[9]*m[2]*m[15] - m[9]*m[3]*m[14] - m[13]*m[2]*m[11] + m[13]*m[3]*m[10];
    inv[5]  =  m[0]*m[10]*m[15] - m[0]*m[11]*m[14] - m[8]*m[2]*m[15] + m[8]*m[3]*m[14] + m[12]*m[2]*m[11] - m[12]*m[3]*m[10];
    inv[9]  = -m[0]*m[9]*m[15]  + m[0]*m[11]*m[13] + m[8]*m[1]*m[15] - m[8]*m[3]*m[13] - m[12]*m[1]*m[11] + m[12]*m[3]*m[9];
    inv[13] =  m[0]*m[9]*m[14]  - m[0]*m[10]*m[13] - m[8]*m[1]*m[14] + m[8]*m[2]*m[13] + m[12]*m[1]*m[10] - m[12]*m[2]*m[9];
    inv[2]  =  m[1]*m[6]*m[15]  - m[1]*m[7]*m[14]  - m[5]*m[2]*m[15] + m[5]*m[3]*m[14] + m[13]*m[2]*m[7]  - m[13]*m[3]*m[6];
    inv[6]  = -m[0]*m[6]*m[15]  + m[0]*m[7]*m[14]  + m[4]*m[2]*m[15] - m[4]*m[3]*m[14] - m[12]*m[2]*m[7]  + m[12]*m[3]*m[6];
    inv[10] =  m[0]*m[5]*m[15]  - m[0]*m[7]*m[13]  - m[4]*m[1]*m[15] + m[4]*m[3]*m[13] + m[12]*m[1]*m[7]  - m[12]*m[3]*m[5];
    inv[14] = -m[0]*m[5]*m[14]  + m[0]*m[6]*m[13]  + m[4]*m[1]*m[14] - m[4]*m[2]*m[13] - m[12]*m[1]*m[6]  + m[12]*m[2]*m[5];
    inv[3]  = -m[1]*m[6]*m[11]  + m[1]*m[7]*m[10]  + m[5]*m[2]*m[11] - m[5]*m[3]*m[10] - m[9]*m[2]*m[7]   + m[9]*m[3]*m[6];
    inv[7]  =  m[0]*m[6]*m[11]  - m[0]*m[7]*m[10]  - m[4]*m[2]*m[11] + m[4]*m[3]*m[10] + m[8]*m[2]*m[7]   - m[8]*m[3]*m[6];
    inv[11] = -m[0]*m[5]*m[11]  + m[0]*m[7]*m[9]   + m[4]*m[1]*m[11] - m[4]*m[3]*m[9]  - m[8]*m[1]*m[7]   + m[8]*m[3]*m[5];
    inv[15] =  m[0]*m[5]*m[10]  - m[0]*m[6]*m[9]   - m[4]*m[1]*m[10] + m[4]*m[2]*m[9]  + m[8]*m[1]*m[6]   - m[8]*m[2]*m[5];

    double det = m[0]*inv[0] + m[1]*inv[4] + m[2]*inv[8] + m[3]*inv[12];
    double rdet = 1.0 / det;
    #pragma unroll
    for (int i = 0; i < 16; ++i) inv[i] *= rdet;

    #pragma unroll
    for (int i = 0; i < 3; ++i) {
        #pragma unroll
        for (int j = 0; j < 4; ++j) {
            double s = 0.0;
            #pragma unroll
            for (int k = 0; k < 4; ++k)
                s += inv[i * 4 + k] * (double)hist[b * 16 + k * 4 + j];
            T12[b * 12 + i * 4 + j] = (float)s;
        }
    }
}

// --- Pass A: transpose features to channels-last (float4 both sides) ---
__global__ __launch_bounds__(256) void transpose_kernel(
    const float4* __restrict__ feat4,
    const float* __restrict__ sdf,
    const float* __restrict__ occ,
    float4* __restrict__ feat_t4,
    float2* __restrict__ so_t) {

    __shared__ float tile[32][132];   // [c][v], stride 132 (16B-aligned rows)

    const int b     = blockIdx.x / (DHW / 128);
    const int vbase = (blockIdx.x % (DHW / 128)) * 128;
    const int tid   = threadIdx.x;

    const size_t inb4 = ((size_t)b * CD * DHW) >> 2;

    // read: 32 channels x 32 float4-groups of v; 512B contiguous per wave per c
    #pragma unroll
    for (int it = 0; it < 4; ++it) {
        const int idx = it * 256 + tid;   // 0..1023
        const int v4  = idx & 31;
        const int c   = idx >> 5;
        float4 r = feat4[inb4 + (((size_t)c * DHW + vbase) >> 2) + v4];
        *(float4*)&tile[c][v4 * 4] = r;
    }
    if (tid < 128) {
        const size_t v = (size_t)b * DHW + vbase + tid;
        so_t[v] = make_float2(sdf[v], occ[v]);
    }
    __syncthreads();

    // write: channels-last; 8 lanes = one voxel's 32 ch; wave = 1KB contiguous
    const size_t ob = (size_t)b * DHW + vbase;
    #pragma unroll
    for (int it = 0; it < 4; ++it) {
        const int idx = it * 256 + tid;
        const int c4  = idx & 7;
        const int v   = idx >> 3;         // 0..127
        float4 w;
        w.x = tile[c4 * 4 + 0][v];
        w.y = tile[c4 * 4 + 1][v];
        w.z = tile[c4 * 4 + 2][v];
        w.w = tile[c4 * 4 + 3][v];
        feat_t4[(ob + v) * 8 + c4] = w;
    }
}

// --- Pass B: cooperative float4 gather, 8 lanes-per-voxel x 4 ch each ---
__global__ __launch_bounds__(256) void proj2_kernel(
    const float4* __restrict__ feat_t4,
    const float2* __restrict__ so_t,
    const float* __restrict__ T12,
    float* __restrict__ out) {

    __shared__ float2 ow[128][9];     // (off8 bit-cast, weight) per voxel/tap
    __shared__ float  tile[128][33];  // results, pad 33
    __shared__ float  soL[128][2];

    const int b     = blockIdx.x / (DHW / 128);
    const int vbase = (blockIdx.x % (DHW / 128)) * 128;
    const int tid   = threadIdx.x;
    const int bDHW  = b * DHW;

    // ---- Phase 1: one thread per voxel: coords, taps, weights ----
    if (tid < 128) {
        const int v  = vbase + tid;
        const int x  = v % XD;
        const int t1 = v / XD;
        const int y  = t1 % YD;
        const int z  = t1 / YD;

        const float* Tb = T12 + b * 12;
        const float px = x * VOX, py = y * VOX, pz = z * VOX;
        const float hx = Tb[0] * px + Tb[1] * py + Tb[2]  * pz + Tb[3];
        const float hy = Tb[4] * px + Tb[5] * py + Tb[6]  * pz + Tb[7];
        const float hz = Tb[8] * px + Tb[9] * py + Tb[10] * pz + Tb[11];

        const float nx = 2.0f * ((hx / VOX) / 95.0f) - 1.0f;
        const float ny = 2.0f * ((hy / VOX) / 95.0f) - 1.0f;
        const float nz = 2.0f * ((hz / VOX) / 47.0f) - 1.0f;

        float* g = out + GRID_OFF + ((size_t)bDHW + v) * 3;
        g[0] = nx; g[1] = ny; g[2] = nz;

        const float ix = (nx + 1.0f) * 0.5f * 95.0f;
        const float iy = (ny + 1.0f) * 0.5f * 95.0f;
        const float iz = (nz + 1.0f) * 0.5f * 47.0f;

        const float x0f = floorf(ix), y0f = floorf(iy), z0f = floorf(iz);
        const float fx = ix - x0f, fy = iy - y0f, fz = iz - z0f;

        const float wXa[2] = {1.0f - fx, fx};
        const float wYa[2] = {1.0f - fy, fy};
        const float wZa[2] = {1.0f - fz, fz};

        int  cX[2], cY[2], cZ[2];
        bool vX[2], vY[2], vZ[2];
        #pragma unroll
        for (int d = 0; d < 2; ++d) {
            const float xi = x0f + (float)d;
            const float yi = y0f + (float)d;
            const float zi = z0f + (float)d;
            vX[d] = (xi >= 0.0f) && (xi <= 95.0f);
            vY[d] = (yi >= 0.0f) && (yi <= 95.0f);
            vZ[d] = (zi >= 0.0f) && (zi <= 47.0f);
            cX[d] = (int)fminf(fmaxf(xi, 0.0f), 95.0f);
            cY[d] = (int)fminf(fmaxf(yi, 0.0f), 95.0f);
            cZ[d] = (int)fminf(fmaxf(zi, 0.0f), 47.0f);
        }

        #pragma unroll
        for (int j = 0; j < 8; ++j) {
            const int dx = (j >> 2) & 1, dy = (j >> 1) & 1, dz = j & 1;
            const int off = cZ[dz] * HW + cY[dy] * XD + cX[dx];
            const int off8 = (bDHW + off) * 8;   // float4 index into feat_t
            float w = (wXa[dx] * wYa[dy]) * wZa[dz];
            w = (vX[dx] && vY[dy] && vZ[dz]) ? w : 0.0f;
            ow[tid][j] = make_float2(__int_as_float(off8), w);
        }
    }
    __syncthreads();

    // ---- Phase 2: gather. lane = (voxel-octet, channel-quad) ----
    const int wv   = tid >> 6;          // wave 0..3
    const int vsub = (tid >> 3) & 7;    // voxel within 8-group
    const int c4   = tid & 7;           // channel quad

    #pragma unroll 1
    for (int it = 0; it < 4; ++it) {
        const int vl = wv * 32 + it * 8 + vsub;
        float4 acc = make_float4(0.f, 0.f, 0.f, 0.f);
        float2 a2  = make_float2(0.f, 0.f);
        #pragma unroll
        for (int j = 0; j < 8; ++j) {
            const float2 p = ow[vl][j];            // broadcast within octet
            const int off8 = __float_as_int(p.x);
            const float4 f = feat_t4[(size_t)off8 + c4];
            acc.x = fmaf(f.x, p.y, acc.x);
            acc.y = fmaf(f.y, p.y, acc.y);
            acc.z = fmaf(f.z, p.y, acc.z);
            acc.w = fmaf(f.w, p.y, acc.w);
            if (c4 == 0) {
                const float2 s = so_t[(size_t)(off8 >> 3)];
                a2.x = fmaf(s.x, p.y, a2.x);
                a2.y = fmaf(s.y, p.y, a2.y);
            }
        }
        tile[vl][c4 * 4 + 0] = acc.x;
        tile[vl][c4 * 4 + 1] = acc.y;
        tile[vl][c4 * 4 + 2] = acc.z;
        tile[vl][c4 * 4 + 3] = acc.w;
        if (c4 == 0) { soL[vl][0] = a2.x; soL[vl][1] = a2.y; }
    }
    __syncthreads();

    // ---- coalesced float4 output writes ----
    float* ob = out + (size_t)b * CD * DHW + vbase;
    #pragma unroll
    for (int it = 0; it < 4; ++it) {
        const int idx = it * 256 + tid;
        const int v32 = idx & 31;         // float4 group of v
        const int c   = idx >> 5;
        float4 w;
        w.x = tile[v32 * 4 + 0][c];
        w.y = tile[v32 * 4 + 1][c];
        w.z = tile[v32 * 4 + 2][c];
        w.w = tile[v32 * 4 + 3][c];
        *(float4*)&ob[(size_t)c * DHW + v32 * 4] = w;
    }
    {
        const int ch = tid >> 7, vl = tid & 127;
        out[FEAT_N + (size_t)ch * SDF_N + bDHW + vbase + vl] = soL[vl][ch];
    }
}

// --- Fallback (R1 kernel) if workspace is too small for the transpose ---
__global__ __launch_bounds__(256) void proj_kernel(
    const float* __restrict__ feat,
    const float* __restrict__ sdf,
    const float* __restrict__ occ,
    const float* __restrict__ T12,
    float* __restrict__ out) {

    const int b   = blockIdx.x / (DHW / 256);
    const int rem = blockIdx.x % (DHW / 256);
    const int zyx = rem * 256 + threadIdx.x;
    const int x   = zyx % XD;
    const int t1  = zyx / XD;
    const int y   = t1 % YD;
    const int z   = t1 / YD;

    const float* Tb = T12 + b * 12;
    const float px = x * VOX, py = y * VOX, pz = z * VOX;
    const float hx = Tb[0] * px + Tb[1] * py + Tb[2]  * pz + Tb[3];
    const float hy = Tb[4] * px + Tb[5] * py + Tb[6]  * pz + Tb[7];
    const float hz = Tb[8] * px + Tb[9] * py + Tb[10] * pz + Tb[11];

    const float nx = 2.0f * ((hx / VOX) / 95.0f) - 1.0f;
    const float ny = 2.0f * ((hy / VOX) / 95.0f) - 1.0f;
    const float nz = 2.0f * ((hz / VOX) / 47.0f) - 1.0f;

    {
        const long long gbase = GRID_OFF + ((long long)b * DHW + zyx) * 3;
        out[gbase + 0] = nx;
        out[gbase + 1] = ny;
        out[gbase + 2] = nz;
    }

    const float ix = (nx + 1.0f) * 0.5f * 95.0f;
    const float iy = (ny + 1.0f) * 0.5f * 95.0f;
    const float iz = (nz + 1.0f) * 0.5f * 47.0f;

    const float x0f = floorf(ix), y0f = floorf(iy), z0f = floorf(iz);
    const float fx = ix - x0f, fy = iy - y0f, fz = iz - z0f;

    const float wXa[2] = {1.0f - fx, fx};
    const float wYa[2] = {1.0f - fy, fy};
    const float wZa[2] = {1.0f - fz, fz};

    int  cX[2], cY[2], cZ[2];
    bool vX[2], vY[2], vZ[2];
    #pragma unroll
    for (int d = 0; d < 2; ++d) {
        const float xi = x0f + (float)d;
        const float yi = y0f + (float)d;
        const float zi = z0f + (float)d;
        vX[d] = (xi >= 0.0f) && (xi <= 95.0f);
        vY[d] = (yi >= 0.0f) && (yi <= 95.0f);
        vZ[d] = (zi >= 0.0f) && (zi <= 47.0f);
        cX[d] = (int)fminf(fmaxf(xi, 0.0f), 95.0f);
        cY[d] = (int)fminf(fmaxf(yi, 0.0f), 95.0f);
        cZ[d] = (int)fminf(fmaxf(zi, 0.0f), 47.0f);
    }

    int   offs[8];
    float wts[8];
    #pragma unroll
    for (int j = 0; j < 8; ++j) {
        const int dx = (j >> 2) & 1, dy = (j >> 1) & 1, dz = j & 1;
        offs[j] = cZ[dz] * HW + cY[dy] * XD + cX[dx];
        float w = (wXa[dx] * wYa[dy]) * wZa[dz];
        wts[j] = (vX[dx] && vY[dy] && vZ[dz]) ? w : 0.0f;
    }

    const float* fb = feat + (long long)b * CD * DHW;
    float* ob = out + (long long)b * CD * DHW + zyx;
    #pragma unroll 4
    for (int cc = 0; cc < CD; ++cc) {
        const float* p = fb + (long long)cc * DHW;
        float acc = 0.0f;
        #pragma unroll
        for (int j = 0; j < 8; ++j) acc += p[offs[j]] * wts[j];
        ob[(long long)cc * DHW] = acc;
    }
    {
        const float* p = sdf + (long long)b * DHW;
        float acc = 0.0f;
        #pragma unroll
        for (int j = 0; j < 8; ++j) acc += p[offs[j]] * wts[j];
        out[FEAT_N + (long long)b * DHW + zyx] = acc;
    }
    {
        const float* p = occ + (long long)b * DHW;
        float acc = 0.0f;
        #pragma unroll
        for (int j = 0; j < 8; ++j) acc += p[offs[j]] * wts[j];
        out[FEAT_N + SDF_N + (long long)b * DHW + zyx] = acc;
    }
}

extern "C" void kernel_launch(void* const* d_in, const int* in_sizes, int n_in,
                              void* d_out, int out_size, void* d_ws, size_t ws_size,
                              hipStream_t stream) {
    const float* feat = (const float*)d_in[0];
    const float* sdf  = (const float*)d_in[1];
    const float* occ  = (const float*)d_in[2];
    const float* hist = (const float*)d_in[3];
    const float* cur  = (const float*)d_in[4];
    float* out = (float*)d_out;

    const size_t need = (size_t)(FEAT_N + 2 * SDF_N) * sizeof(float) + 512;

    if (ws_size >= need) {
        float4* feat_t4 = (float4*)d_ws;                  // [B,DHW,32] as float4
        float2* so_t    = (float2*)((char*)d_ws + (size_t)FEAT_N * sizeof(float));
        float*  T12     = (float*)((char*)d_ws + (size_t)(FEAT_N + 2 * SDF_N) * sizeof(float));

        make_transform_kernel<<<1, BD, 0, stream>>>(hist, cur, T12);
        transpose_kernel<<<BD * (DHW / 128), 256, 0, stream>>>((const float4*)feat, sdf, occ, feat_t4, so_t);
        proj2_kernel<<<BD * (DHW / 128), 256, 0, stream>>>((const float4*)feat_t4, so_t, T12, out);
    } else {
        float* T12 = (float*)d_ws;
        make_transform_kernel<<<1, BD, 0, stream>>>(hist, cur, T12);
        proj_kernel<<<BD * (DHW / 256), 256, 0, stream>>>(feat, sdf, occ, T12, out);
    }
}

// Round 4
// 1052.074 us; speedup vs baseline: 1.6395x; 1.0523x over previous
//
#include <hip/hip_runtime.h>

// ---------------------------------------------------------------------------
// PoseProjection: T = inv(current) @ historical; trilinear grid_sample of
// features[8,32,48,96,96], sdf[8,1,...], occ[8,1,...] at the transformed
// voxel grid; also outputs the normalized grid [8,48,96,96,3].
// Outputs concatenated: feat(113246208) | sdf(3538944) | occ(3538944) | grid(10616832)
//
// Structure (R2-R4): transpose feat -> channels-last feat_t[B,DHW,32] in ws,
// then cooperative float4 gather (8 lanes x float4 = one 128B tap).
// R4: full-block phase-1 (256 voxels/block), sdf/occ+grid handled in phase-1
// (grid via LDS-staged float4 stores), unroll-2 gather ILP, XCD-batch swizzle
// (blockIdx&7 = batch) so each XCD's gather window (~2 input z-planes, 2.4MB)
// stays L2-resident.
// NOTE: ~550us of dur_us is fixed harness overhead (0xAA poison + d_in
// restore) measured via R1/R2 gap arithmetic; kernel budget is dur - 550.
// ---------------------------------------------------------------------------

#define XD 96
#define YD 96
#define ZD 48
#define BD 8
#define CD 32

constexpr float VOX = 0.0625f;
constexpr int   HW   = YD * XD;          // 9216
constexpr int   DHW  = ZD * HW;          // 442368
constexpr long long FEAT_N = (long long)BD * CD * DHW;  // 113246208
constexpr long long SDF_N  = (long long)BD * DHW;       // 3538944
constexpr long long GRID_OFF = FEAT_N + 2 * SDF_N;

// --- Kernel 1: per-batch transform via double-precision adjugate inverse ---
__global__ void make_transform_kernel(const float* __restrict__ hist,
                                      const float* __restrict__ cur,
                                      float* __restrict__ T12) {
    int b = threadIdx.x;
    if (b >= BD) return;
    double m[16], inv[16];
    #pragma unroll
    for (int i = 0; i < 16; ++i) m[i] = (double)cur[b * 16 + i];

    inv[0]  =  m[5]*m[10]*m[15] - m[5]*m[11]*m[14] - m[9]*m[6]*m[15] + m[9]*m[7]*m[14] + m[13]*m[6]*m[11] - m[13]*m[7]*m[10];
    inv[4]  = -m[4]*m[10]*m[15] + m[4]*m[11]*m[14] + m[8]*m[6]*m[15] - m[8]*m[7]*m[14] - m[12]*m[6]*m[11] + m[12]*m[7]*m[10];
    inv[8]  =  m[4]*m[9]*m[15]  - m[4]*m[11]*m[13] - m[8]*m[5]*m[15] + m[8]*m[7]*m[13] + m[12]*m[5]*m[11] - m[12]*m[7]*m[9];
    inv[12] = -m[4]*m[9]*m[14]  + m[4]*m[10]*m[13] + m[8]*m[5]*m[14] - m[8]*m[6]*m[13] - m[12]*m[5]*m[10] + m[12]*m[6]*m[9];
    inv[1]  = -m[1]*m[10]*m[15] + m[1]*m[11]*m[14] + m[9]*m[2]*m[15] - m[9]*m[3]*m[14] - m[13]*m[2]*m[11] + m[13]*m[3]*m[10];
    inv[5]  =  m[0]*m[10]*m[15] - m[0]*m[11]*m[14] - m[8]*m[2]*m[15] + m[8]*m[3]*m[14] + m[12]*m[2]*m[11] - m[12]*m[3]*m[10];
    inv[9]  = -m[0]*m[9]*m[15]  + m[0]*m[11]*m[13] + m[8]*m[1]*m[15] - m[8]*m[3]*m[13] - m[12]*m[1]*m[11] + m[12]*m[3]*m[9];
    inv[13] =  m[0]*m[9]*m[14]  - m[0]*m[10]*m[13] - m[8]*m[1]*m[14] + m[8]*m[2]*m[13] + m[12]*m[1]*m[10] - m[12]*m[2]*m[9];
    inv[2]  =  m[1]*m[6]*m[15]  - m[1]*m[7]*m[14]  - m[5]*m[2]*m[15] + m[5]*m[3]*m[14] + m[13]*m[2]*m[7]  - m[13]*m[3]*m[6];
    inv[6]  = -m[0]*m[6]*m[15]  + m[0]*m[7]*m[14]  + m[4]*m[2]*m[15] - m[4]*m[3]*m[14] - m[12]*m[2]*m[7]  + m[12]*m[3]*m[6];
    inv[10] =  m[0]*m[5]*m[15]  - m[0]*m[7]*m[13]  - m[4]*m[1]*m[15] + m[4]*m[3]*m[13] + m[12]*m[1]*m[7]  - m[12]*m[3]*m[5];
    inv[14] = -m[0]*m[5]*m[14]  + m[0]*m[6]*m[13]  + m[4]*m[1]*m[14] - m[4]*m[2]*m[13] - m[12]*m[1]*m[6]  + m[12]*m[2]*m[5];
    inv[3]  = -m[1]*m[6]*m[11]  + m[1]*m[7]*m[10]  + m[5]*m[2]*m[11] - m[5]*m[3]*m[10] - m[9]*m[2]*m[7]   + m[9]*m[3]*m[6];
    inv[7]  =  m[0]*m[6]*m[11]  - m[0]*m[7]*m[10]  - m[4]*m[2]*m[11] + m[4]*m[3]*m[10] + m[8]*m[2]*m[7]   - m[8]*m[3]*m[6];
    inv[11] = -m[0]*m[5]*m[11]  + m[0]*m[7]*m[9]   + m[4]*m[1]*m[11] - m[4]*m[3]*m[9]  - m[8]*m[1]*m[7]   + m[8]*m[3]*m[5];
    inv[15] =  m[0]*m[5]*m[10]  - m[0]*m[6]*m[9]   - m[4]*m[1]*m[10] + m[4]*m[2]*m[9]  + m[8]*m[1]*m[6]   - m[8]*m[2]*m[5];

    double det = m[0]*inv[0] + m[1]*inv[4] + m[2]*inv[8] + m[3]*inv[12];
    double rdet = 1.0 / det;
    #pragma unroll
    for (int i = 0; i < 16; ++i) inv[i] *= rdet;

    #pragma unroll
    for (int i = 0; i < 3; ++i) {
        #pragma unroll
        for (int j = 0; j < 4; ++j) {
            double s = 0.0;
            #pragma unroll
            for (int k = 0; k < 4; ++k)
                s += inv[i * 4 + k] * (double)hist[b * 16 + k * 4 + j];
            T12[b * 12 + i * 4 + j] = (float)s;
        }
    }
}

// --- Pass A: transpose features to channels-last (float4 both sides) ---
__global__ __launch_bounds__(256) void transpose_kernel(
    const float4* __restrict__ feat4,
    const float* __restrict__ sdf,
    const float* __restrict__ occ,
    float4* __restrict__ feat_t4,
    float2* __restrict__ so_t) {

    __shared__ float tile[32][132];   // [c][v], stride 132 (16B-aligned rows)

    const int bid   = blockIdx.x;
    const int b     = bid & 7;                 // XCD-batch swizzle
    const int vbase = (bid >> 3) * 128;
    const int tid   = threadIdx.x;

    const size_t inb4 = ((size_t)b * CD * DHW) >> 2;

    #pragma unroll
    for (int it = 0; it < 4; ++it) {
        const int idx = it * 256 + tid;   // 0..1023
        const int v4  = idx & 31;
        const int c   = idx >> 5;
        float4 r = feat4[inb4 + (((size_t)c * DHW + vbase) >> 2) + v4];
        *(float4*)&tile[c][v4 * 4] = r;
    }
    if (tid < 128) {
        const size_t v = (size_t)b * DHW + vbase + tid;
        so_t[v] = make_float2(sdf[v], occ[v]);
    }
    __syncthreads();

    const size_t ob = (size_t)b * DHW + vbase;
    #pragma unroll
    for (int it = 0; it < 4; ++it) {
        const int idx = it * 256 + tid;
        const int c4  = idx & 7;
        const int v   = idx >> 3;         // 0..127
        float4 w;
        w.x = tile[c4 * 4 + 0][v];
        w.y = tile[c4 * 4 + 1][v];
        w.z = tile[c4 * 4 + 2][v];
        w.w = tile[c4 * 4 + 3][v];
        feat_t4[(ob + v) * 8 + c4] = w;
    }
}

// --- Pass B: cooperative float4 gather, 256 voxels/block, full phase-1 ---
__global__ __launch_bounds__(256, 4) void proj2_kernel(
    const float4* __restrict__ feat_t4,
    const float2* __restrict__ so_t,
    const float* __restrict__ T12,
    float* __restrict__ out) {

    __shared__ float2 ow[256][9];     // (off8 bit-cast, weight) per voxel/tap
    __shared__ float  tile[128][33];  // results for one 128-voxel sub-tile
    __shared__ float  gbuf[768];      // grid coords staging for float4 stores

    const int bid   = blockIdx.x;
    const int b     = bid & 7;                 // XCD-batch swizzle
    const int vbase = (bid >> 3) * 256;
    const int tid   = threadIdx.x;
    const int bDHW  = b * DHW;

    // ---- Phase 1: every thread computes one voxel: coords, taps, sdf/occ ----
    {
        const int v  = vbase + tid;
        const int x  = v % XD;
        const int t1 = v / XD;
        const int y  = t1 % YD;
        const int z  = t1 / YD;

        const float* Tb = T12 + b * 12;
        const float px = x * VOX, py = y * VOX, pz = z * VOX;
        const float hx = Tb[0] * px + Tb[1] * py + Tb[2]  * pz + Tb[3];
        const float hy = Tb[4] * px + Tb[5] * py + Tb[6]  * pz + Tb[7];
        const float hz = Tb[8] * px + Tb[9] * py + Tb[10] * pz + Tb[11];

        const float nx = 2.0f * ((hx / VOX) / 95.0f) - 1.0f;
        const float ny = 2.0f * ((hy / VOX) / 95.0f) - 1.0f;
        const float nz = 2.0f * ((hz / VOX) / 47.0f) - 1.0f;

        gbuf[tid * 3 + 0] = nx;
        gbuf[tid * 3 + 1] = ny;
        gbuf[tid * 3 + 2] = nz;

        const float ix = (nx + 1.0f) * 0.5f * 95.0f;
        const float iy = (ny + 1.0f) * 0.5f * 95.0f;
        const float iz = (nz + 1.0f) * 0.5f * 47.0f;

        const float x0f = floorf(ix), y0f = floorf(iy), z0f = floorf(iz);
        const float fx = ix - x0f, fy = iy - y0f, fz = iz - z0f;

        const float wXa[2] = {1.0f - fx, fx};
        const float wYa[2] = {1.0f - fy, fy};
        const float wZa[2] = {1.0f - fz, fz};

        int  cX[2], cY[2], cZ[2];
        bool vX[2], vY[2], vZ[2];
        #pragma unroll
        for (int d = 0; d < 2; ++d) {
            const float xi = x0f + (float)d;
            const float yi = y0f + (float)d;
            const float zi = z0f + (float)d;
            vX[d] = (xi >= 0.0f) && (xi <= 95.0f);
            vY[d] = (yi >= 0.0f) && (yi <= 95.0f);
            vZ[d] = (zi >= 0.0f) && (zi <= 47.0f);
            cX[d] = (int)fminf(fmaxf(xi, 0.0f), 95.0f);
            cY[d] = (int)fminf(fmaxf(yi, 0.0f), 95.0f);
            cZ[d] = (int)fminf(fmaxf(zi, 0.0f), 47.0f);
        }

        float2 a2 = make_float2(0.f, 0.f);
        #pragma unroll
        for (int j = 0; j < 8; ++j) {
            const int dx = (j >> 2) & 1, dy = (j >> 1) & 1, dz = j & 1;
            const int off = cZ[dz] * HW + cY[dy] * XD + cX[dx];
            const int off8 = (bDHW + off) * 8;   // float4 index into feat_t
            float w = (wXa[dx] * wYa[dy]) * wZa[dz];
            w = (vX[dx] && vY[dy] && vZ[dz]) ? w : 0.0f;
            ow[tid][j] = make_float2(__int_as_float(off8), w);
            const float2 s = so_t[(size_t)(off8 >> 3)];
            a2.x = fmaf(s.x, w, a2.x);
            a2.y = fmaf(s.y, w, a2.y);
        }
        out[FEAT_N + (size_t)bDHW + v]         = a2.x;   // sdf (coalesced)
        out[FEAT_N + SDF_N + (size_t)bDHW + v] = a2.y;   // occ (coalesced)
    }
    __syncthreads();

    // ---- grid output: 768 consecutive floats -> 192 float4 stores ----
    if (tid < 192) {
        float4 gv = *(const float4*)&gbuf[tid * 4];
        *(float4*)(out + GRID_OFF + ((size_t)bDHW + vbase) * 3 + tid * 4) = gv;
    }

    // ---- Phase 2: gather. lane = (voxel-octet, channel-quad) ----
    const int wv   = tid >> 6;          // wave 0..3
    const int vsub = (tid >> 3) & 7;    // voxel within octet
    const int c4   = tid & 7;           // channel quad
    float* ob = out + (size_t)b * CD * DHW + vbase;

    #pragma unroll
    for (int t = 0; t < 2; ++t) {
        #pragma unroll 2
        for (int it = 0; it < 4; ++it) {
            const int vl = wv * 32 + it * 8 + vsub;   // 0..127 (sub-tile local)
            const int ov = t * 128 + vl;              // 0..255 (block voxel)
            float4 acc = make_float4(0.f, 0.f, 0.f, 0.f);
            #pragma unroll
            for (int j = 0; j < 8; ++j) {
                const float2 p = ow[ov][j];           // broadcast within octet
                const int off8 = __float_as_int(p.x);
                const float4 f = feat_t4[(size_t)off8 + c4];
                acc.x = fmaf(f.x, p.y, acc.x);
                acc.y = fmaf(f.y, p.y, acc.y);
                acc.z = fmaf(f.z, p.y, acc.z);
                acc.w = fmaf(f.w, p.y, acc.w);
            }
            tile[vl][c4 * 4 + 0] = acc.x;
            tile[vl][c4 * 4 + 1] = acc.y;
            tile[vl][c4 * 4 + 2] = acc.z;
            tile[vl][c4 * 4 + 3] = acc.w;
        }
        __syncthreads();

        // coalesced float4 stores of this 128-voxel sub-tile
        #pragma unroll
        for (int it2 = 0; it2 < 4; ++it2) {
            const int idx = it2 * 256 + tid;
            const int v32 = idx & 31;         // float4 group of v
            const int c   = idx >> 5;
            float4 w;
            w.x = tile[v32 * 4 + 0][c];
            w.y = tile[v32 * 4 + 1][c];
            w.z = tile[v32 * 4 + 2][c];
            w.w = tile[v32 * 4 + 3][c];
            *(float4*)&ob[(size_t)c * DHW + t * 128 + v32 * 4] = w;
        }
        __syncthreads();
    }
}

// --- Fallback (R1 kernel) if workspace is too small for the transpose ---
__global__ __launch_bounds__(256) void proj_kernel(
    const float* __restrict__ feat,
    const float* __restrict__ sdf,
    const float* __restrict__ occ,
    const float* __restrict__ T12,
    float* __restrict__ out) {

    const int b   = blockIdx.x / (DHW / 256);
    const int rem = blockIdx.x % (DHW / 256);
    const int zyx = rem * 256 + threadIdx.x;
    const int x   = zyx % XD;
    const int t1  = zyx / XD;
    const int y   = t1 % YD;
    const int z   = t1 / YD;

    const float* Tb = T12 + b * 12;
    const float px = x * VOX, py = y * VOX, pz = z * VOX;
    const float hx = Tb[0] * px + Tb[1] * py + Tb[2]  * pz + Tb[3];
    const float hy = Tb[4] * px + Tb[5] * py + Tb[6]  * pz + Tb[7];
    const float hz = Tb[8] * px + Tb[9] * py + Tb[10] * pz + Tb[11];

    const float nx = 2.0f * ((hx / VOX) / 95.0f) - 1.0f;
    const float ny = 2.0f * ((hy / VOX) / 95.0f) - 1.0f;
    const float nz = 2.0f * ((hz / VOX) / 47.0f) - 1.0f;

    {
        const long long gbase = GRID_OFF + ((long long)b * DHW + zyx) * 3;
        out[gbase + 0] = nx;
        out[gbase + 1] = ny;
        out[gbase + 2] = nz;
    }

    const float ix = (nx + 1.0f) * 0.5f * 95.0f;
    const float iy = (ny + 1.0f) * 0.5f * 95.0f;
    const float iz = (nz + 1.0f) * 0.5f * 47.0f;

    const float x0f = floorf(ix), y0f = floorf(iy), z0f = floorf(iz);
    const float fx = ix - x0f, fy = iy - y0f, fz = iz - z0f;

    const float wXa[2] = {1.0f - fx, fx};
    const float wYa[2] = {1.0f - fy, fy};
    const float wZa[2] = {1.0f - fz, fz};

    int  cX[2], cY[2], cZ[2];
    bool vX[2], vY[2], vZ[2];
    #pragma unroll
    for (int d = 0; d < 2; ++d) {
        const float xi = x0f + (float)d;
        const float yi = y0f + (float)d;
        const float zi = z0f + (float)d;
        vX[d] = (xi >= 0.0f) && (xi <= 95.0f);
        vY[d] = (yi >= 0.0f) && (yi <= 95.0f);
        vZ[d] = (zi >= 0.0f) && (zi <= 47.0f);
        cX[d] = (int)fminf(fmaxf(xi, 0.0f), 95.0f);
        cY[d] = (int)fminf(fmaxf(yi, 0.0f), 95.0f);
        cZ[d] = (int)fminf(fmaxf(zi, 0.0f), 47.0f);
    }

    int   offs[8];
    float wts[8];
    #pragma unroll
    for (int j = 0; j < 8; ++j) {
        const int dx = (j >> 2) & 1, dy = (j >> 1) & 1, dz = j & 1;
        offs[j] = cZ[dz] * HW + cY[dy] * XD + cX[dx];
        float w = (wXa[dx] * wYa[dy]) * wZa[dz];
        wts[j] = (vX[dx] && vY[dy] && vZ[dz]) ? w : 0.0f;
    }

    const float* fb = feat + (long long)b * CD * DHW;
    float* ob = out + (long long)b * CD * DHW + zyx;
    #pragma unroll 4
    for (int cc = 0; cc < CD; ++cc) {
        const float* p = fb + (long long)cc * DHW;
        float acc = 0.0f;
        #pragma unroll
        for (int j = 0; j < 8; ++j) acc += p[offs[j]] * wts[j];
        ob[(long long)cc * DHW] = acc;
    }
    {
        const float* p = sdf + (long long)b * DHW;
        float acc = 0.0f;
        #pragma unroll
        for (int j = 0; j < 8; ++j) acc += p[offs[j]] * wts[j];
        out[FEAT_N + (long long)b * DHW + zyx] = acc;
    }
    {
        const float* p = occ + (long long)b * DHW;
        float acc = 0.0f;
        #pragma unroll
        for (int j = 0; j < 8; ++j) acc += p[offs[j]] * wts[j];
        out[FEAT_N + SDF_N + (long long)b * DHW + zyx] = acc;
    }
}

extern "C" void kernel_launch(void* const* d_in, const int* in_sizes, int n_in,
                              void* d_out, int out_size, void* d_ws, size_t ws_size,
                              hipStream_t stream) {
    const float* feat = (const float*)d_in[0];
    const float* sdf  = (const float*)d_in[1];
    const float* occ  = (const float*)d_in[2];
    const float* hist = (const float*)d_in[3];
    const float* cur  = (const float*)d_in[4];
    float* out = (float*)d_out;

    const size_t need = (size_t)(FEAT_N + 2 * SDF_N) * sizeof(float) + 512;

    if (ws_size >= need) {
        float4* feat_t4 = (float4*)d_ws;                  // [B,DHW,32] as float4
        float2* so_t    = (float2*)((char*)d_ws + (size_t)FEAT_N * sizeof(float));
        float*  T12     = (float*)((char*)d_ws + (size_t)(FEAT_N + 2 * SDF_N) * sizeof(float));

        make_transform_kernel<<<1, BD, 0, stream>>>(hist, cur, T12);
        transpose_kernel<<<BD * (DHW / 128), 256, 0, stream>>>((const float4*)feat, sdf, occ, feat_t4, so_t);
        proj2_kernel<<<BD * (DHW / 256), 256, 0, stream>>>((const float4*)feat_t4, so_t, T12, out);
    } else {
        float* T12 = (float*)d_ws;
        make_transform_kernel<<<1, BD, 0, stream>>>(hist, cur, T12);
        proj_kernel<<<BD * (DHW / 256), 256, 0, stream>>>(feat, sdf, occ, T12, out);
    }
}

// Round 5
// 969.979 us; speedup vs baseline: 1.7782x; 1.0846x over previous
//
#include <hip/hip_runtime.h>
#include <hip/hip_fp16.h>

// ---------------------------------------------------------------------------
// PoseProjection: T = inv(current) @ historical; trilinear grid_sample of
// features[8,32,48,96,96], sdf[8,1,...], occ[8,1,...] at the transformed
// voxel grid; also outputs the normalized grid [8,48,96,96,3].
// Outputs concatenated: feat(113246208) | sdf(3538944) | occ(3538944) | grid(10616832)
//
// R5: fp16 channels-last staging. feat_h[B*DHW][32] halfs (64 B/voxel) so an
// x-pair of trilinear taps is 128 B contiguous -> one line per pair (~6
// line-accesses/voxel vs 8). sdf/occ staged as duplicated fp16 x-pairs
// (8 B aligned) -> 4 accesses/voxel vs 8. TA model (calibrated on R1-R4:
// ~2 cyc/line-access) says proj2 drops ~270 -> ~150 us; transpose writes
// halve (226 MB). ~550 us of dur_us is fixed harness poison overhead.
// ---------------------------------------------------------------------------

#define XD 96
#define YD 96
#define ZD 48
#define BD 8
#define CD 32

constexpr float VOX = 0.0625f;
constexpr int   HW   = YD * XD;          // 9216
constexpr int   DHW  = ZD * HW;          // 442368
constexpr long long FEAT_N = (long long)BD * CD * DHW;  // 113246208
constexpr long long SDF_N  = (long long)BD * DHW;       // 3538944
constexpr long long GRID_OFF = FEAT_N + 2 * SDF_N;

__device__ __forceinline__ unsigned h2u(__half2 h) {
    union { __half2 h; unsigned u; } c; c.h = h; return c.u;
}
__device__ __forceinline__ __half2 u2h(unsigned u) {
    union { unsigned u; __half2 h; } c; c.u = u; return c.h;
}

// --- Kernel 1: per-batch transform via double-precision adjugate inverse ---
__global__ void make_transform_kernel(const float* __restrict__ hist,
                                      const float* __restrict__ cur,
                                      float* __restrict__ T12) {
    int b = threadIdx.x;
    if (b >= BD) return;
    double m[16], inv[16];
    #pragma unroll
    for (int i = 0; i < 16; ++i) m[i] = (double)cur[b * 16 + i];

    inv[0]  =  m[5]*m[10]*m[15] - m[5]*m[11]*m[14] - m[9]*m[6]*m[15] + m[9]*m[7]*m[14] + m[13]*m[6]*m[11] - m[13]*m[7]*m[10];
    inv[4]  = -m[4]*m[10]*m[15] + m[4]*m[11]*m[14] + m[8]*m[6]*m[15] - m[8]*m[7]*m[14] - m[12]*m[6]*m[11] + m[12]*m[7]*m[10];
    inv[8]  =  m[4]*m[9]*m[15]  - m[4]*m[11]*m[13] - m[8]*m[5]*m[15] + m[8]*m[7]*m[13] + m[12]*m[5]*m[11] - m[12]*m[7]*m[9];
    inv[12] = -m[4]*m[9]*m[14]  + m[4]*m[10]*m[13] + m[8]*m[5]*m[14] - m[8]*m[6]*m[13] - m[12]*m[5]*m[10] + m[12]*m[6]*m[9];
    inv[1]  = -m[1]*m[10]*m[15] + m[1]*m[11]*m[14] + m[9]*m[2]*m[15] - m[9]*m[3]*m[14] - m[13]*m[2]*m[11] + m[13]*m[3]*m[10];
    inv[5]  =  m[0]*m[10]*m[15] - m[0]*m[11]*m[14] - m[8]*m[2]*m[15] + m[8]*m[3]*m[14] + m[12]*m[2]*m[11] - m[12]*m[3]*m[10];
    inv[9]  = -m[0]*m[9]*m[15]  + m[0]*m[11]*m[13] + m[8]*m[1]*m[15] - m[8]*m[3]*m[13] - m[12]*m[1]*m[11] + m[12]*m[3]*m[9];
    inv[13] =  m[0]*m[9]*m[14]  - m[0]*m[10]*m[13] - m[8]*m[1]*m[14] + m[8]*m[2]*m[13] + m[12]*m[1]*m[10] - m[12]*m[2]*m[9];
    inv[2]  =  m[1]*m[6]*m[15]  - m[1]*m[7]*m[14]  - m[5]*m[2]*m[15] + m[5]*m[3]*m[14] + m[13]*m[2]*m[7]  - m[13]*m[3]*m[6];
    inv[6]  = -m[0]*m[6]*m[15]  + m[0]*m[7]*m[14]  + m[4]*m[2]*m[15] - m[4]*m[3]*m[14] - m[12]*m[2]*m[7]  + m[12]*m[3]*m[6];
    inv[10] =  m[0]*m[5]*m[15]  - m[0]*m[7]*m[13]  - m[4]*m[1]*m[15] + m[4]*m[3]*m[13] + m[12]*m[1]*m[7]  - m[12]*m[3]*m[5];
    inv[14] = -m[0]*m[5]*m[14]  + m[0]*m[6]*m[13]  + m[4]*m[1]*m[14] - m[4]*m[2]*m[13] - m[12]*m[1]*m[6]  + m[12]*m[2]*m[5];
    inv[3]  = -m[1]*m[6]*m[11]  + m[1]*m[7]*m[10]  + m[5]*m[2]*m[11] - m[5]*m[3]*m[10] - m[9]*m[2]*m[7]   + m[9]*m[3]*m[6];
    inv[7]  =  m[0]*m[6]*m[11]  - m[0]*m[7]*m[10]  - m[4]*m[2]*m[11] + m[4]*m[3]*m[10] + m[8]*m[2]*m[7]   - m[8]*m[3]*m[6];
    inv[11] = -m[0]*m[5]*m[11]  + m[0]*m[7]*m[9]   + m[4]*m[1]*m[11] - m[4]*m[3]*m[9]  - m[8]*m[1]*m[7]   + m[8]*m[3]*m[5];
    inv[15] =  m[0]*m[5]*m[10]  - m[0]*m[6]*m[9]   - m[4]*m[1]*m[10] + m[4]*m[2]*m[9]  + m[8]*m[1]*m[6]   - m[8]*m[2]*m[5];

    double det = m[0]*inv[0] + m[1]*inv[4] + m[2]*inv[8] + m[3]*inv[12];
    double rdet = 1.0 / det;
    #pragma unroll
    for (int i = 0; i < 16; ++i) inv[i] *= rdet;

    #pragma unroll
    for (int i = 0; i < 3; ++i) {
        #pragma unroll
        for (int j = 0; j < 4; ++j) {
            double s = 0.0;
            #pragma unroll
            for (int k = 0; k < 4; ++k)
                s += inv[i * 4 + k] * (double)hist[b * 16 + k * 4 + j];
            T12[b * 12 + i * 4 + j] = (float)s;
        }
    }
}

// --- Pass A: transpose features to channels-last fp16 + build so_dup pairs ---
__global__ __launch_bounds__(256) void transpose_kernel(
    const float4* __restrict__ feat4,
    const float* __restrict__ sdf,
    const float* __restrict__ occ,
    uint4* __restrict__ feat_h4,      // [B*DHW][4] : 4 x (8 halfs)
    uint2* __restrict__ so_dup) {     // [B*DHW] : {h2(sdf,occ)@v, h2@v+1}

    __shared__ float tile[32][132];   // [c][v]

    const int bid   = blockIdx.x;
    const int b     = bid & 7;                 // XCD-batch swizzle
    const int vbase = (bid >> 3) * 128;
    const int tid   = threadIdx.x;

    const size_t inb4 = ((size_t)b * CD * DHW) >> 2;

    #pragma unroll
    for (int it = 0; it < 4; ++it) {
        const int idx = it * 256 + tid;   // 0..1023
        const int v4  = idx & 31;
        const int c   = idx >> 5;
        float4 r = feat4[inb4 + (((size_t)c * DHW + vbase) >> 2) + v4];
        *(float4*)&tile[c][v4 * 4] = r;
    }
    if (tid < 128) {
        const size_t v  = (size_t)b * DHW + vbase + tid;
        const size_t v1 = (v + 1 < (size_t)BD * DHW) ? v + 1 : v;
        uint2 sd;
        sd.x = h2u(__float22half2_rn(make_float2(sdf[v],  occ[v])));
        sd.y = h2u(__float22half2_rn(make_float2(sdf[v1], occ[v1])));
        so_dup[v] = sd;
    }
    __syncthreads();

    // write: channels-last fp16; lanes consecutive in c8 -> 1KB contiguous/wave
    const size_t ob = (size_t)b * DHW + vbase;
    #pragma unroll
    for (int it = 0; it < 2; ++it) {
        const int idx = it * 256 + tid;   // 0..511
        const int c8  = idx & 3;          // which 8-channel group
        const int v   = idx >> 2;         // 0..127
        float f0 = tile[c8 * 8 + 0][v], f1 = tile[c8 * 8 + 1][v];
        float f2 = tile[c8 * 8 + 2][v], f3 = tile[c8 * 8 + 3][v];
        float f4 = tile[c8 * 8 + 4][v], f5 = tile[c8 * 8 + 5][v];
        float f6 = tile[c8 * 8 + 6][v], f7 = tile[c8 * 8 + 7][v];
        uint4 o;
        o.x = h2u(__float22half2_rn(make_float2(f0, f1)));
        o.y = h2u(__float22half2_rn(make_float2(f2, f3)));
        o.z = h2u(__float22half2_rn(make_float2(f4, f5)));
        o.w = h2u(__float22half2_rn(make_float2(f6, f7)));
        feat_h4[(ob + v) * 4 + c8] = o;
    }
}

// --- Pass B: paired fp16 gather; octet = 2 x-sides x 4 channel-groups ---
__global__ __launch_bounds__(256, 4) void proj2_kernel(
    const uint4* __restrict__ feat_h4,
    const uint2* __restrict__ so_dup,
    const float* __restrict__ T12,
    float* __restrict__ out) {

    __shared__ float4 ow4[256][4];    // per voxel, per (dy,dz) pair: off,wl,wh
    __shared__ float  tile[128][33];  // results for one 128-voxel sub-tile
    __shared__ float  gbuf[768];      // grid coords staging

    const int bid   = blockIdx.x;
    const int b     = bid & 7;                 // XCD-batch swizzle
    const int vbase = (bid >> 3) * 256;
    const int tid   = threadIdx.x;
    const int bDHW  = b * DHW;

    // ---- Phase 1: per-voxel coords, pair descriptors, sdf/occ gather ----
    {
        const int v  = vbase + tid;
        const int x  = v % XD;
        const int t1 = v / XD;
        const int y  = t1 % YD;
        const int z  = t1 / YD;

        const float* Tb = T12 + b * 12;
        const float px = x * VOX, py = y * VOX, pz = z * VOX;
        const float hx = Tb[0] * px + Tb[1] * py + Tb[2]  * pz + Tb[3];
        const float hy = Tb[4] * px + Tb[5] * py + Tb[6]  * pz + Tb[7];
        const float hz = Tb[8] * px + Tb[9] * py + Tb[10] * pz + Tb[11];

        const float nx = 2.0f * ((hx / VOX) / 95.0f) - 1.0f;
        const float ny = 2.0f * ((hy / VOX) / 95.0f) - 1.0f;
        const float nz = 2.0f * ((hz / VOX) / 47.0f) - 1.0f;

        gbuf[tid * 3 + 0] = nx;
        gbuf[tid * 3 + 1] = ny;
        gbuf[tid * 3 + 2] = nz;

        const float ix = (nx + 1.0f) * 0.5f * 95.0f;
        const float iy = (ny + 1.0f) * 0.5f * 95.0f;
        const float iz = (nz + 1.0f) * 0.5f * 47.0f;

        const float x0f = floorf(ix), y0f = floorf(iy), z0f = floorf(iz);
        const float fx = ix - x0f, fy = iy - y0f, fz = iz - z0f;

        const float wXa[2] = {1.0f - fx, fx};
        const float wYa[2] = {1.0f - fy, fy};
        const float wZa[2] = {1.0f - fz, fz};

        int  cX[2], cY[2], cZ[2];
        bool vX[2], vY[2], vZ[2];
        #pragma unroll
        for (int d = 0; d < 2; ++d) {
            const float xi = x0f + (float)d;
            const float yi = y0f + (float)d;
            const float zi = z0f + (float)d;
            vX[d] = (xi >= 0.0f) && (xi <= 95.0f);
            vY[d] = (yi >= 0.0f) && (yi <= 95.0f);
            vZ[d] = (zi >= 0.0f) && (zi <= 47.0f);
            cX[d] = (int)fminf(fmaxf(xi, 0.0f), 95.0f);
            cY[d] = (int)fminf(fmaxf(yi, 0.0f), 95.0f);
            cZ[d] = (int)fminf(fmaxf(zi, 0.0f), 47.0f);
        }

        // x-pair remap to base blo in [0,94]; weights assigned by absolute x
        const float w0 = vX[0] ? wXa[0] : 0.0f;
        const float w1 = vX[1] ? wXa[1] : 0.0f;
        const int   blo = (cX[0] < 94) ? cX[0] : 94;
        const float wl = ((cX[0] == blo) ? w0 : 0.0f) + ((cX[1] == blo) ? w1 : 0.0f);
        const float wh = ((cX[0] == blo + 1) ? w0 : 0.0f) + ((cX[1] == blo + 1) ? w1 : 0.0f);

        float2 a2 = make_float2(0.f, 0.f);
        #pragma unroll
        for (int p = 0; p < 4; ++p) {
            const int dy = p & 1, dz = p >> 1;
            float wyz = wYa[dy] * wZa[dz];
            wyz = (vY[dy] && vZ[dz]) ? wyz : 0.0f;
            const float wlp = wl * wyz, whp = wh * wyz;
            const int offp = bDHW + cZ[dz] * HW + cY[dy] * XD + blo;
            ow4[tid][p] = make_float4(__int_as_float(offp), wlp, whp, 0.0f);

            const uint2 sd = so_dup[(size_t)offp];
            const float2 s0 = __half22float2(u2h(sd.x));
            const float2 s1 = __half22float2(u2h(sd.y));
            a2.x += s0.x * wlp + s1.x * whp;
            a2.y += s0.y * wlp + s1.y * whp;
        }
        out[FEAT_N + (size_t)bDHW + v]         = a2.x;   // sdf (coalesced)
        out[FEAT_N + SDF_N + (size_t)bDHW + v] = a2.y;   // occ (coalesced)
    }
    __syncthreads();

    // ---- grid output: 768 consecutive floats -> 192 float4 stores ----
    if (tid < 192) {
        float4 gv = *(const float4*)&gbuf[tid * 4];
        *(float4*)(out + GRID_OFF + ((size_t)bDHW + vbase) * 3 + tid * 4) = gv;
    }

    // ---- Phase 2: paired gather. octet lane = (x-side, channel-8-group) ----
    const int ovb  = tid >> 3;          // voxel slot 0..31 per pass
    const int l    = tid & 7;
    const int side = l >> 2;            // 0 = x-lo, 1 = x-hi
    const int cq   = l & 3;             // 8-channel group
    float* ob = out + (size_t)b * CD * DHW + vbase;

    #pragma unroll
    for (int h = 0; h < 2; ++h) {
        #pragma unroll 2
        for (int it = 0; it < 4; ++it) {
            const int vl = it * 32 + ovb;         // 0..127 sub-tile local
            const int ov = h * 128 + vl;          // block voxel
            float acc[8] = {0.f, 0.f, 0.f, 0.f, 0.f, 0.f, 0.f, 0.f};
            #pragma unroll
            for (int p = 0; p < 4; ++p) {
                const float4 d = ow4[ov][p];      // octet broadcast
                const int offp = __float_as_int(d.x);
                const float w  = side ? d.z : d.y;
                const uint4 fv = feat_h4[(size_t)offp * 4 + l];  // 16B: side*64+cq*16
                float2 f;
                f = __half22float2(u2h(fv.x)); acc[0] += f.x * w; acc[1] += f.y * w;
                f = __half22float2(u2h(fv.y)); acc[2] += f.x * w; acc[3] += f.y * w;
                f = __half22float2(u2h(fv.z)); acc[4] += f.x * w; acc[5] += f.y * w;
                f = __half22float2(u2h(fv.w)); acc[6] += f.x * w; acc[7] += f.y * w;
            }
            #pragma unroll
            for (int k = 0; k < 8; ++k) acc[k] += __shfl_xor(acc[k], 4);
            if (side == 0) {
                #pragma unroll
                for (int k = 0; k < 8; ++k) tile[vl][cq * 8 + k] = acc[k];
            }
        }
        __syncthreads();

        // coalesced float4 stores of this 128-voxel sub-tile
        #pragma unroll
        for (int it2 = 0; it2 < 4; ++it2) {
            const int idx = it2 * 256 + tid;
            const int v32 = idx & 31;
            const int c   = idx >> 5;
            float4 w;
            w.x = tile[v32 * 4 + 0][c];
            w.y = tile[v32 * 4 + 1][c];
            w.z = tile[v32 * 4 + 2][c];
            w.w = tile[v32 * 4 + 3][c];
            *(float4*)&ob[(size_t)c * DHW + h * 128 + v32 * 4] = w;
        }
        __syncthreads();
    }
}

// --- Fallback (R1 kernel) if workspace is too small ---
__global__ __launch_bounds__(256) void proj_kernel(
    const float* __restrict__ feat,
    const float* __restrict__ sdf,
    const float* __restrict__ occ,
    const float* __restrict__ T12,
    float* __restrict__ out) {

    const int b   = blockIdx.x / (DHW / 256);
    const int rem = blockIdx.x % (DHW / 256);
    const int zyx = rem * 256 + threadIdx.x;
    const int x   = zyx % XD;
    const int t1  = zyx / XD;
    const int y   = t1 % YD;
    const int z   = t1 / YD;

    const float* Tb = T12 + b * 12;
    const float px = x * VOX, py = y * VOX, pz = z * VOX;
    const float hx = Tb[0] * px + Tb[1] * py + Tb[2]  * pz + Tb[3];
    const float hy = Tb[4] * px + Tb[5] * py + Tb[6]  * pz + Tb[7];
    const float hz = Tb[8] * px + Tb[9] * py + Tb[10] * pz + Tb[11];

    const float nx = 2.0f * ((hx / VOX) / 95.0f) - 1.0f;
    const float ny = 2.0f * ((hy / VOX) / 95.0f) - 1.0f;
    const float nz = 2.0f * ((hz / VOX) / 47.0f) - 1.0f;

    {
        const long long gbase = GRID_OFF + ((long long)b * DHW + zyx) * 3;
        out[gbase + 0] = nx;
        out[gbase + 1] = ny;
        out[gbase + 2] = nz;
    }

    const float ix = (nx + 1.0f) * 0.5f * 95.0f;
    const float iy = (ny + 1.0f) * 0.5f * 95.0f;
    const float iz = (nz + 1.0f) * 0.5f * 47.0f;

    const float x0f = floorf(ix), y0f = floorf(iy), z0f = floorf(iz);
    const float fx = ix - x0f, fy = iy - y0f, fz = iz - z0f;

    const float wXa[2] = {1.0f - fx, fx};
    const float wYa[2] = {1.0f - fy, fy};
    const float wZa[2] = {1.0f - fz, fz};

    int  cX[2], cY[2], cZ[2];
    bool vX[2], vY[2], vZ[2];
    #pragma unroll
    for (int d = 0; d < 2; ++d) {
        const float xi = x0f + (float)d;
        const float yi = y0f + (float)d;
        const float zi = z0f + (float)d;
        vX[d] = (xi >= 0.0f) && (xi <= 95.0f);
        vY[d] = (yi >= 0.0f) && (yi <= 95.0f);
        vZ[d] = (zi >= 0.0f) && (zi <= 47.0f);
        cX[d] = (int)fminf(fmaxf(xi, 0.0f), 95.0f);
        cY[d] = (int)fminf(fmaxf(yi, 0.0f), 95.0f);
        cZ[d] = (int)fminf(fmaxf(zi, 0.0f), 47.0f);
    }

    int   offs[8];
    float wts[8];
    #pragma unroll
    for (int j = 0; j < 8; ++j) {
        const int dx = (j >> 2) & 1, dy = (j >> 1) & 1, dz = j & 1;
        offs[j] = cZ[dz] * HW + cY[dy] * XD + cX[dx];
        float w = (wXa[dx] * wYa[dy]) * wZa[dz];
        wts[j] = (vX[dx] && vY[dy] && vZ[dz]) ? w : 0.0f;
    }

    const float* fb = feat + (long long)b * CD * DHW;
    float* ob = out + (long long)b * CD * DHW + zyx;
    #pragma unroll 4
    for (int cc = 0; cc < CD; ++cc) {
        const float* p = fb + (long long)cc * DHW;
        float acc = 0.0f;
        #pragma unroll
        for (int j = 0; j < 8; ++j) acc += p[offs[j]] * wts[j];
        ob[(long long)cc * DHW] = acc;
    }
    {
        const float* p = sdf + (long long)b * DHW;
        float acc = 0.0f;
        #pragma unroll
        for (int j = 0; j < 8; ++j) acc += p[offs[j]] * wts[j];
        out[FEAT_N + (long long)b * DHW + zyx] = acc;
    }
    {
        const float* p = occ + (long long)b * DHW;
        float acc = 0.0f;
        #pragma unroll
        for (int j = 0; j < 8; ++j) acc += p[offs[j]] * wts[j];
        out[FEAT_N + SDF_N + (long long)b * DHW + zyx] = acc;
    }
}

extern "C" void kernel_launch(void* const* d_in, const int* in_sizes, int n_in,
                              void* d_out, int out_size, void* d_ws, size_t ws_size,
                              hipStream_t stream) {
    const float* feat = (const float*)d_in[0];
    const float* sdf  = (const float*)d_in[1];
    const float* occ  = (const float*)d_in[2];
    const float* hist = (const float*)d_in[3];
    const float* cur  = (const float*)d_in[4];
    float* out = (float*)d_out;

    // ws layout: feat_h (FEAT_N halfs) | so_dup (B*DHW uint2) | T12
    const size_t feat_h_bytes = (size_t)FEAT_N * 2;                 // ~226.5 MB
    const size_t so_bytes     = (size_t)BD * DHW * sizeof(uint2);   // ~28.3 MB
    const size_t need         = feat_h_bytes + so_bytes + 512;

    if (ws_size >= need) {
        uint4* feat_h4 = (uint4*)d_ws;
        uint2* so_dup  = (uint2*)((char*)d_ws + feat_h_bytes);
        float* T12     = (float*)((char*)d_ws + feat_h_bytes + so_bytes);

        make_transform_kernel<<<1, BD, 0, stream>>>(hist, cur, T12);
        transpose_kernel<<<BD * (DHW / 128), 256, 0, stream>>>(
            (const float4*)feat, sdf, occ, feat_h4, so_dup);
        proj2_kernel<<<BD * (DHW / 256), 256, 0, stream>>>(
            (const uint4*)feat_h4, (const uint2*)so_dup, T12, out);
    } else {
        float* T12 = (float*)d_ws;
        make_transform_kernel<<<1, BD, 0, stream>>>(hist, cur, T12);
        proj_kernel<<<BD * (DHW / 256), 256, 0, stream>>>(feat, sdf, occ, T12, out);
    }
}